// Round 13
// baseline (115.914 us; speedup 1.0000x reference)
//
#include <hip/hip_runtime.h>
#include <math.h>

// Problem constants (B, D, C) from the reference.
#define NB 4096
#define ND 3072
#define NC 10
#define NM 9   // C-1

static constexpr float kEps      = 0.1f;
static constexpr float kNumStab  = 1e-6f;
static constexpr float kAlpha    = 1.0f - (float)NC * kNumStab;  // 1 - C*num_stab
static constexpr float kInvSqrtC = 0.31622776601683794f;         // 1/sqrt(10)

// ---------------------------------------------------------------------------
// R12 post-mortem: the 1-block/CU LDS monolith is structurally latency-bound
// (3 profiles: VALUBusy 22%, occupancy 35%, VGPR stuck at 64, 43-50 µs).
// Key realization: W is row-major, so the W block a lane needs for data
// float4 f (rows d=4f..4f+3) is 10 CONTIGUOUS float4s at W4[10f] — serve W
// straight from L1/L2. No transpose, no LDS staging, no barriers, no 123 KB
// LDS -> real occupancy and a simple streaming loop the scheduler can pipeline.
// ---------------------------------------------------------------------------

// Kernel A: Gram upper triangle. 55 blocks, one (j,k) pair each; W is L2-hot.
__global__ __launch_bounds__(256) void gram_kernel(
        const float* __restrict__ W, float* __restrict__ G) {
    int e = blockIdx.x, j = 0;
    while (e >= NC - j) { e -= NC - j; ++j; }   // (j,k) from triangle index
    const int k = j + e;
    float acc = 0.0f;
    for (int d = threadIdx.x; d < ND; d += 256)
        acc = fmaf(W[d * NC + j], W[d * NC + k], acc);
    #pragma unroll
    for (int off = 32; off > 0; off >>= 1) acc += __shfl_xor(acc, off, 64);
    __shared__ float part[4];
    if ((threadIdx.x & 63) == 0) part[threadIdx.x >> 6] = acc;
    __syncthreads();
    if (threadIdx.x == 0) {
        const float g = part[0] + part[1] + part[2] + part[3];
        G[j * NC + k] = g;
        G[k * NC + j] = g;
    }
}

// Kernel B: main. 1024 blocks x 256 threads; wave = 1 sample. Per lane per
// iteration: 1 coalesced data float4 + 10 contiguous W float4 + 40 FMAs.
// 16 independent waves/CU hide L2/HBM latency; LDS = 416 B.
__global__ __launch_bounds__(256, 4) void main_kernel(
        const float* __restrict__ data, const float* __restrict__ W,
        const float* __restrict__ G, float* __restrict__ out) {
    __shared__ float Gs[100];
    __shared__ float regs[4];

    const int tid  = threadIdx.x;
    const int lane = tid & 63;
    const int wv   = tid >> 6;

    if (tid < 100) Gs[tid] = G[tid];
    __syncthreads();

    const int s = blockIdx.x * 4 + wv;               // this wave's sample
    const float4* d4 = reinterpret_cast<const float4*>(data) + (size_t)s * (ND / 4);
    const float4* W4 = reinterpret_cast<const float4*>(W);

    float acc[NC];
    #pragma unroll
    for (int k = 0; k < NC; ++k) acc[k] = 0.0f;

    #pragma unroll 2
    for (int it = 0; it < 12; ++it) {
        const int f = it * 64 + lane;                // float4 index in the row
        const float4 x = d4[f];                      // coalesced data load
        const float4* wp = W4 + (size_t)f * 10;      // rows d=4f..4f+3 of W
        float4 wq[10];
        #pragma unroll
        for (int jj = 0; jj < 10; ++jj) wq[jj] = wp[jj];   // 10 indep loads (ILP)
        const float xs[4] = {x.x, x.y, x.z, x.w};
        // element m of the 40-float chunk: d-offset m/10, class k = m%10
        #pragma unroll
        for (int jj = 0; jj < 10; ++jj) {
            const int mb = 4 * jj;
            acc[(mb + 0) % 10] = fmaf(xs[(mb + 0) / 10], wq[jj].x, acc[(mb + 0) % 10]);
            acc[(mb + 1) % 10] = fmaf(xs[(mb + 1) / 10], wq[jj].y, acc[(mb + 1) % 10]);
            acc[(mb + 2) % 10] = fmaf(xs[(mb + 2) / 10], wq[jj].z, acc[(mb + 2) % 10]);
            acc[(mb + 3) % 10] = fmaf(xs[(mb + 3) / 10], wq[jj].w, acc[(mb + 3) % 10]);
        }
    }

    // In-wave butterfly: every lane ends with the full z[10] for its sample.
    #pragma unroll
    for (int k = 0; k < NC; ++k) {
        float v = acc[k];
        #pragma unroll
        for (int off = 32; off > 0; off >>= 1) v += __shfl_xor(v, off, 64);
        acc[k] = v;
    }

    // Analytic epilogue on lane 0 (math identical to the absmax-0.0 version).
    if (lane == 0) {
        float z[NC];
        #pragma unroll
        for (int k = 0; k < NC; ++k) z[k] = acc[k];

        float zm = z[0];
        #pragma unroll
        for (int k = 1; k < NC; ++k) zm = fmaxf(zm, z[k]);
        float e[NC], Zs = 0.0f;
        #pragma unroll
        for (int k = 0; k < NC; ++k) { e[k] = expf(z[k] - zm); Zs += e[k]; }
        const float inv = 1.0f / Zs;

        float sg[NC], p[NC], sq[NC], u[NC];
        #pragma unroll
        for (int k = 0; k < NC; ++k) {
            sg[k] = e[k] * inv;                 // softmax probs (sigma)
            p[k]  = kAlpha * sg[k] + kNumStab;  // stabilized probs
            sq[k] = sqrtf(p[k]);                // s
            u[k]  = sg[k] / sq[k];              // sigma / s
        }
        const float qd = 1.0f - sq[NM];

        // v = G*sigma, t = sigma^T G sigma
        float v[NC], t = 0.0f;
        #pragma unroll
        for (int k = 0; k < NC; ++k) {
            float a = 0.0f;
            #pragma unroll
            for (int j = 0; j < NC; ++j) a = fmaf(Gs[k * NC + j], sg[j], a);
            v[k] = a;
            t = fmaf(sg[k], a, t);
        }
        const float vM = v[NM], uM = u[NM];
        const float QMM = Gs[NC * NC - 1] - 2.0f * vM + t;

        float sumJ = 0.0f;
        #pragma unroll
        for (int i = 0; i < NM; ++i) {
            const float Qii = Gs[i * NC + i] - 2.0f * v[i] + t;
            const float QiM = Gs[i * NC + NM] - v[i] - vM + t;
            const float r = sq[i] / qd;
            sumJ += u[i] * u[i] * Qii
                  + 2.0f * u[i] * uM * r * QiM
                  + uM * uM * r * r * QMM;
        }
        const float jn = (kAlpha / qd) * sqrtf(fmaxf(sumJ, 0.0f));

        float ssum = 0.0f;
        #pragma unroll
        for (int k = 0; k < NC; ++k) ssum += sq[k];
        const float ac = fminf(1.0f, fmaxf(-1.0f, ssum * kInvSqrtC));
        const float delta = 2.0f * acosf(ac);

        float psum = 0.0f;
        #pragma unroll
        for (int k = 0; k < NM; ++k) psum += p[k];
        const float rho = (2.0f * qd - psum) / qd;

        const float a = jn - delta / (rho * kEps);
        regs[wv] = (a > 0.0f) ? a : expm1f(a);
    }
    __syncthreads();
    if (tid == 0) {
        atomicAdd(out, (regs[0] + regs[1] + regs[2] + regs[3]) * (1.0f / (float)NB));
    }
}

extern "C" void kernel_launch(void* const* d_in, const int* in_sizes, int n_in,
                              void* d_out, int out_size, void* d_ws, size_t ws_size,
                              hipStream_t stream) {
    const float* data = (const float*)d_in[0];
    const float* W    = (const float*)d_in[1];
    float* out = (float*)d_out;
    float* G   = (float*)d_ws;   // 100 floats; poison runs before us anyway

    // d_out is re-poisoned to 0xAA before every timed launch -> zero it ourselves.
    hipMemsetAsync(out, 0, sizeof(float), stream);
    gram_kernel<<<(NC * (NC + 1)) / 2, 256, 0, stream>>>(W, G);
    main_kernel<<<NB / 4, 256, 0, stream>>>(data, W, G, out);
}

// Round 14
// 99.459 us; speedup vs baseline: 1.1655x; 1.1655x over previous
//
#include <hip/hip_runtime.h>
#include <math.h>

// Problem constants (B, D, C) from the reference.
#define NB 4096
#define ND 3072
#define NC 10
#define NM 9   // C-1
#define NF (ND / 4)   // 768 float4 per Wt row

static constexpr float kEps      = 0.1f;
static constexpr float kNumStab  = 1e-6f;
static constexpr float kAlpha    = 1.0f - (float)NC * kNumStab;  // 1 - C*num_stab
static constexpr float kInvSqrtC = 0.31622776601683794f;         // 1/sqrt(10)

// ---------------------------------------------------------------------------
// R13 post-mortem: streaming kernel stuck at 45-50 µs with VALUBusy 16%, HBM
// 7% -> neither pipe bound. Culprit: W4+10f gives 160 B lane stride, so each
// W-load instruction touches 64 DISTINCT cache lines; ~640 line-transactions
// per wave-iter * 16 waves * 12 iters ~ 123 K cyc/CU ~ 51 µs = the measured
// time. Fix: transpose W once into workspace (Wt[k][d]); then every load in
// the hot loop is lane-consecutive (16 lines/instr, 4x fewer transactions,
// L1-hot). Wave owns 2 samples to halve per-sample W traffic.
// ---------------------------------------------------------------------------

// Kernel 0: Wt[k][d] = W[d][k]. 30 blocks; scalar gathers (L2-hot), coalesced
// float4 writes. ~2 µs.
__global__ __launch_bounds__(256) void transpose_kernel(
        const float* __restrict__ W, float* __restrict__ Wt) {
    const int c = blockIdx.x * 256 + threadIdx.x;   // output float4 id
    if (c >= NC * NF) return;
    const int k = c / NF;
    const int m = c - k * NF;
    float4 v;
    v.x = W[(4 * m + 0) * NC + k];
    v.y = W[(4 * m + 1) * NC + k];
    v.z = W[(4 * m + 2) * NC + k];
    v.w = W[(4 * m + 3) * NC + k];
    reinterpret_cast<float4*>(Wt)[c] = v;
}

// Kernel 1: Gram upper triangle from Wt — fully coalesced row dots. 55 blocks.
__global__ __launch_bounds__(256) void gram_kernel(
        const float* __restrict__ Wt, float* __restrict__ G) {
    int e = blockIdx.x, j = 0;
    while (e >= NC - j) { e -= NC - j; ++j; }   // (j,k) from triangle index
    const int k = j + e;
    const float4* a = reinterpret_cast<const float4*>(Wt) + j * NF;
    const float4* b = reinterpret_cast<const float4*>(Wt) + k * NF;
    float acc = 0.0f;
    for (int i = threadIdx.x; i < NF; i += 256) {
        const float4 av = a[i], bv = b[i];
        acc += av.x * bv.x + av.y * bv.y + av.z * bv.z + av.w * bv.w;
    }
    #pragma unroll
    for (int off = 32; off > 0; off >>= 1) acc += __shfl_xor(acc, off, 64);
    __shared__ float part[4];
    if ((threadIdx.x & 63) == 0) part[threadIdx.x >> 6] = acc;
    __syncthreads();
    if (threadIdx.x == 0) {
        const float g = part[0] + part[1] + part[2] + part[3];
        G[j * NC + k] = g;
        G[k * NC + j] = g;
    }
}

// Kernel 2: main. 512 blocks x 256 threads; each wave owns 2 samples over the
// full D. Per wave-iter: 2 coalesced data float4 loads + 10 coalesced Wt
// loads (16 lines each, L1-shared across the block's 4 waves) + 80 FMAs.
__global__ __launch_bounds__(256, 2) void main_kernel(
        const float* __restrict__ data, const float* __restrict__ Wt,
        const float* __restrict__ G, float* __restrict__ out) {
    __shared__ float Gs[100];
    __shared__ float regs[8];

    const int tid  = threadIdx.x;
    const int lane = tid & 63;
    const int wv   = tid >> 6;

    if (tid < 100) Gs[tid] = G[tid];
    __syncthreads();

    const int s0 = blockIdx.x * 8 + wv * 2;          // this wave's 2 samples
    const float4* d0 = reinterpret_cast<const float4*>(data) + (size_t)s0 * NF;
    const float4* d1 = d0 + NF;
    const float4* Wt4 = reinterpret_cast<const float4*>(Wt);

    float acc[2][NC];
    #pragma unroll
    for (int s = 0; s < 2; ++s)
        #pragma unroll
        for (int k = 0; k < NC; ++k) acc[s][k] = 0.0f;

    #pragma unroll 2
    for (int it = 0; it < 12; ++it) {
        const int f = it * 64 + lane;
        const float4 x0 = d0[f];                     // coalesced (HBM/L3)
        const float4 x1 = d1[f];
        float4 wq[NC];
        #pragma unroll
        for (int k = 0; k < NC; ++k) wq[k] = Wt4[k * NF + f];  // coalesced, L1-hot
        #pragma unroll
        for (int k = 0; k < NC; ++k) {
            acc[0][k] = fmaf(x0.x, wq[k].x, acc[0][k]);
            acc[0][k] = fmaf(x0.y, wq[k].y, acc[0][k]);
            acc[0][k] = fmaf(x0.z, wq[k].z, acc[0][k]);
            acc[0][k] = fmaf(x0.w, wq[k].w, acc[0][k]);
            acc[1][k] = fmaf(x1.x, wq[k].x, acc[1][k]);
            acc[1][k] = fmaf(x1.y, wq[k].y, acc[1][k]);
            acc[1][k] = fmaf(x1.z, wq[k].z, acc[1][k]);
            acc[1][k] = fmaf(x1.w, wq[k].w, acc[1][k]);
        }
    }

    // In-wave butterfly: every lane ends with full z[10] for both samples.
    #pragma unroll
    for (int s = 0; s < 2; ++s)
        #pragma unroll
        for (int k = 0; k < NC; ++k) {
            float v = acc[s][k];
            #pragma unroll
            for (int off = 32; off > 0; off >>= 1) v += __shfl_xor(v, off, 64);
            acc[s][k] = v;
        }

    // Analytic epilogue: lane 0 -> sample s0, lane 1 -> sample s0+1.
    if (lane < 2) {
        float z[NC];
        #pragma unroll
        for (int k = 0; k < NC; ++k) z[k] = (lane == 0) ? acc[0][k] : acc[1][k];

        float zm = z[0];
        #pragma unroll
        for (int k = 1; k < NC; ++k) zm = fmaxf(zm, z[k]);
        float e[NC], Zs = 0.0f;
        #pragma unroll
        for (int k = 0; k < NC; ++k) { e[k] = expf(z[k] - zm); Zs += e[k]; }
        const float inv = 1.0f / Zs;

        float sg[NC], p[NC], sq[NC], u[NC];
        #pragma unroll
        for (int k = 0; k < NC; ++k) {
            sg[k] = e[k] * inv;                 // softmax probs (sigma)
            p[k]  = kAlpha * sg[k] + kNumStab;  // stabilized probs
            sq[k] = sqrtf(p[k]);                // s
            u[k]  = sg[k] / sq[k];              // sigma / s
        }
        const float qd = 1.0f - sq[NM];

        // v = G*sigma, t = sigma^T G sigma
        float v[NC], t = 0.0f;
        #pragma unroll
        for (int k = 0; k < NC; ++k) {
            float a = 0.0f;
            #pragma unroll
            for (int j = 0; j < NC; ++j) a = fmaf(Gs[k * NC + j], sg[j], a);
            v[k] = a;
            t = fmaf(sg[k], a, t);
        }
        const float vM = v[NM], uM = u[NM];
        const float QMM = Gs[NC * NC - 1] - 2.0f * vM + t;

        float sumJ = 0.0f;
        #pragma unroll
        for (int i = 0; i < NM; ++i) {
            const float Qii = Gs[i * NC + i] - 2.0f * v[i] + t;
            const float QiM = Gs[i * NC + NM] - v[i] - vM + t;
            const float r = sq[i] / qd;
            sumJ += u[i] * u[i] * Qii
                  + 2.0f * u[i] * uM * r * QiM
                  + uM * uM * r * r * QMM;
        }
        const float jn = (kAlpha / qd) * sqrtf(fmaxf(sumJ, 0.0f));

        float ssum = 0.0f;
        #pragma unroll
        for (int k = 0; k < NC; ++k) ssum += sq[k];
        const float ac = fminf(1.0f, fmaxf(-1.0f, ssum * kInvSqrtC));
        const float delta = 2.0f * acosf(ac);

        float psum = 0.0f;
        #pragma unroll
        for (int k = 0; k < NM; ++k) psum += p[k];
        const float rho = (2.0f * qd - psum) / qd;

        const float a = jn - delta / (rho * kEps);
        regs[wv * 2 + lane] = (a > 0.0f) ? a : expm1f(a);
    }
    __syncthreads();
    if (tid == 0) {
        float bs = 0.0f;
        #pragma unroll
        for (int i = 0; i < 8; ++i) bs += regs[i];
        atomicAdd(out, bs * (1.0f / (float)NB));
    }
}

extern "C" void kernel_launch(void* const* d_in, const int* in_sizes, int n_in,
                              void* d_out, int out_size, void* d_ws, size_t ws_size,
                              hipStream_t stream) {
    const float* data = (const float*)d_in[0];
    const float* W    = (const float*)d_in[1];
    float* out = (float*)d_out;
    float* Wt  = (float*)d_ws;            // NC*ND floats (120 KB)
    float* G   = Wt + NC * ND;            // 100 floats

    // d_out is re-poisoned to 0xAA before every timed launch -> zero it ourselves.
    hipMemsetAsync(out, 0, sizeof(float), stream);
    transpose_kernel<<<(NC * NF + 255) / 256, 256, 0, stream>>>(W, Wt);
    gram_kernel<<<(NC * (NC + 1)) / 2, 256, 0, stream>>>(Wt, G);
    main_kernel<<<NB / 8, 256, 0, stream>>>(data, Wt, G, out);
}

// Round 18
// 97.252 us; speedup vs baseline: 1.1919x; 1.0227x over previous
//
#include <hip/hip_runtime.h>
#include <math.h>

// Problem constants (B, D, C) from the reference.
#define NB 4096
#define ND 3072
#define NC 10
#define NM 9   // C-1
#define NF (ND / 4)   // 768 float4 per Wt row

static constexpr float kEps      = 0.1f;
static constexpr float kNumStab  = 1e-6f;
static constexpr float kAlpha    = 1.0f - (float)NC * kNumStab;  // 1 - C*num_stab
static constexpr float kInvSqrtC = 0.31622776601683794f;         // 1/sqrt(10)

// ---------------------------------------------------------------------------
// R14: main_kernel (Wt-coalesced streaming) dropped below profiler top-5 —
// the 160 B-stride transaction disaster is fixed. Remaining controllable cost
// is launch structure: 4 dispatches/iteration. This round fuses
// {memset(out), transpose, gram} into ONE 85-block prep kernel (main kernel
// byte-identical to R14 for clean attribution):
//   blocks 0-29 : Wt[k][d] = W[d][k]            (R13-verified code)
//   blocks 30-84: Gram triangle straight from W  (R12-verified code)
//   block 0/tid 0 also zeroes out (replaces hipMemsetAsync; stream-ordered
//   before main_kernel's atomicAdds).
// ---------------------------------------------------------------------------

__global__ __launch_bounds__(256) void prep_kernel(
        const float* __restrict__ W, float* __restrict__ Wt,
        float* __restrict__ G, float* __restrict__ out) {
    if (blockIdx.x < 30) {
        // ---- transpose: output float4 id c covers rows d=4m..4m+3, class k.
        if (blockIdx.x == 0 && threadIdx.x == 0) out[0] = 0.0f;
        const int c = blockIdx.x * 256 + threadIdx.x;   // 7680 = 30*256 exactly
        const int k = c / NF;
        const int m = c - k * NF;
        float4 v;
        v.x = W[(4 * m + 0) * NC + k];
        v.y = W[(4 * m + 1) * NC + k];
        v.z = W[(4 * m + 2) * NC + k];
        v.w = W[(4 * m + 3) * NC + k];
        reinterpret_cast<float4*>(Wt)[c] = v;
    } else {
        // ---- Gram upper-triangle entry (j,k) straight from W (L2-hot).
        int e = blockIdx.x - 30, j = 0;
        while (e >= NC - j) { e -= NC - j; ++j; }
        const int k = j + e;
        float acc = 0.0f;
        for (int d = threadIdx.x; d < ND; d += 256)
            acc = fmaf(W[d * NC + j], W[d * NC + k], acc);
        #pragma unroll
        for (int off = 32; off > 0; off >>= 1) acc += __shfl_xor(acc, off, 64);
        __shared__ float part[4];
        if ((threadIdx.x & 63) == 0) part[threadIdx.x >> 6] = acc;
        __syncthreads();
        if (threadIdx.x == 0) {
            const float g = part[0] + part[1] + part[2] + part[3];
            G[j * NC + k] = g;
            G[k * NC + j] = g;
        }
    }
}

// Main kernel: byte-identical to R14 (passed, absmax 0.0, <41 µs).
// 512 blocks x 256 threads; each wave owns 2 samples over the full D.
__global__ __launch_bounds__(256, 2) void main_kernel(
        const float* __restrict__ data, const float* __restrict__ Wt,
        const float* __restrict__ G, float* __restrict__ out) {
    __shared__ float Gs[100];
    __shared__ float regs[8];

    const int tid  = threadIdx.x;
    const int lane = tid & 63;
    const int wv   = tid >> 6;

    if (tid < 100) Gs[tid] = G[tid];
    __syncthreads();

    const int s0 = blockIdx.x * 8 + wv * 2;          // this wave's 2 samples
    const float4* d0 = reinterpret_cast<const float4*>(data) + (size_t)s0 * NF;
    const float4* d1 = d0 + NF;
    const float4* Wt4 = reinterpret_cast<const float4*>(Wt);

    float acc[2][NC];
    #pragma unroll
    for (int s = 0; s < 2; ++s)
        #pragma unroll
        for (int k = 0; k < NC; ++k) acc[s][k] = 0.0f;

    #pragma unroll 2
    for (int it = 0; it < 12; ++it) {
        const int f = it * 64 + lane;
        const float4 x0 = d0[f];                     // coalesced (HBM/L3)
        const float4 x1 = d1[f];
        float4 wq[NC];
        #pragma unroll
        for (int k = 0; k < NC; ++k) wq[k] = Wt4[k * NF + f];  // coalesced, L1-hot
        #pragma unroll
        for (int k = 0; k < NC; ++k) {
            acc[0][k] = fmaf(x0.x, wq[k].x, acc[0][k]);
            acc[0][k] = fmaf(x0.y, wq[k].y, acc[0][k]);
            acc[0][k] = fmaf(x0.z, wq[k].z, acc[0][k]);
            acc[0][k] = fmaf(x0.w, wq[k].w, acc[0][k]);
            acc[1][k] = fmaf(x1.x, wq[k].x, acc[1][k]);
            acc[1][k] = fmaf(x1.y, wq[k].y, acc[1][k]);
            acc[1][k] = fmaf(x1.z, wq[k].z, acc[1][k]);
            acc[1][k] = fmaf(x1.w, wq[k].w, acc[1][k]);
        }
    }

    // In-wave butterfly: every lane ends with full z[10] for both samples.
    #pragma unroll
    for (int s = 0; s < 2; ++s)
        #pragma unroll
        for (int k = 0; k < NC; ++k) {
            float v = acc[s][k];
            #pragma unroll
            for (int off = 32; off > 0; off >>= 1) v += __shfl_xor(v, off, 64);
            acc[s][k] = v;
        }

    // Analytic epilogue: lane 0 -> sample s0, lane 1 -> sample s0+1.
    if (lane < 2) {
        float z[NC];
        #pragma unroll
        for (int k = 0; k < NC; ++k) z[k] = (lane == 0) ? acc[0][k] : acc[1][k];

        float zm = z[0];
        #pragma unroll
        for (int k = 1; k < NC; ++k) zm = fmaxf(zm, z[k]);
        float e[NC], Zs = 0.0f;
        #pragma unroll
        for (int k = 0; k < NC; ++k) { e[k] = expf(z[k] - zm); Zs += e[k]; }
        const float inv = 1.0f / Zs;

        float sg[NC], p[NC], sq[NC], u[NC];
        #pragma unroll
        for (int k = 0; k < NC; ++k) {
            sg[k] = e[k] * inv;                 // softmax probs (sigma)
            p[k]  = kAlpha * sg[k] + kNumStab;  // stabilized probs
            sq[k] = sqrtf(p[k]);                // s
            u[k]  = sg[k] / sq[k];              // sigma / s
        }
        const float qd = 1.0f - sq[NM];

        // v = G*sigma, t = sigma^T G sigma
        float v[NC], t = 0.0f;
        #pragma unroll
        for (int k = 0; k < NC; ++k) {
            float a = 0.0f;
            #pragma unroll
            for (int j = 0; j < NC; ++j) a = fmaf(Gs[k * NC + j], sg[j], a);
            v[k] = a;
            t = fmaf(sg[k], a, t);
        }
        const float vM = v[NM], uM = u[NM];
        const float QMM = Gs[NC * NC - 1] - 2.0f * vM + t;

        float sumJ = 0.0f;
        #pragma unroll
        for (int i = 0; i < NM; ++i) {
            const float Qii = Gs[i * NC + i] - 2.0f * v[i] + t;
            const float QiM = Gs[i * NC + NM] - v[i] - vM + t;
            const float r = sq[i] / qd;
            sumJ += u[i] * u[i] * Qii
                  + 2.0f * u[i] * uM * r * QiM
                  + uM * uM * r * r * QMM;
        }
        const float jn = (kAlpha / qd) * sqrtf(fmaxf(sumJ, 0.0f));

        float ssum = 0.0f;
        #pragma unroll
        for (int k = 0; k < NC; ++k) ssum += sq[k];
        const float ac = fminf(1.0f, fmaxf(-1.0f, ssum * kInvSqrtC));
        const float delta = 2.0f * acosf(ac);

        float psum = 0.0f;
        #pragma unroll
        for (int k = 0; k < NM; ++k) psum += p[k];
        const float rho = (2.0f * qd - psum) / qd;

        const float a = jn - delta / (rho * kEps);
        regs[wv * 2 + lane] = (a > 0.0f) ? a : expm1f(a);
    }
    __syncthreads();
    if (tid == 0) {
        float bs = 0.0f;
        #pragma unroll
        for (int i = 0; i < 8; ++i) bs += regs[i];
        atomicAdd(out, bs * (1.0f / (float)NB));
    }
}

extern "C" void kernel_launch(void* const* d_in, const int* in_sizes, int n_in,
                              void* d_out, int out_size, void* d_ws, size_t ws_size,
                              hipStream_t stream) {
    const float* data = (const float*)d_in[0];
    const float* W    = (const float*)d_in[1];
    float* out = (float*)d_out;
    float* Wt  = (float*)d_ws;            // NC*ND floats (120 KB)
    float* G   = Wt + NC * ND;            // 100 floats

    // prep zeroes out (replaces hipMemsetAsync), transposes W, computes Gram.
    prep_kernel<<<30 + (NC * (NC + 1)) / 2, 256, 0, stream>>>(W, Wt, G, out);
    main_kernel<<<NB / 8, 256, 0, stream>>>(data, Wt, G, out);
}

// Round 19
// 95.841 us; speedup vs baseline: 1.2094x; 1.0147x over previous
//
#include <hip/hip_runtime.h>
#include <math.h>

// Problem constants (B, D, C) from the reference.
#define NB 4096
#define ND 3072
#define NC 10
#define NM 9   // C-1
#define NF (ND / 4)   // 768 float4 per Wt row

static constexpr float kEps      = 0.1f;
static constexpr float kNumStab  = 1e-6f;
static constexpr float kAlpha    = 1.0f - (float)NC * kNumStab;  // 1 - C*num_stab
static constexpr float kInvSqrtC = 0.31622776601683794f;         // 1/sqrt(10)

// ---------------------------------------------------------------------------
// R18 budget: 97.25 = 43 (harness 256MB fill) + ~4 prep + ~36-40 MAIN + gaps.
// Main's stall: Wt (120 KB) > L1 (32 KB) so wq loads are ~200 cyc L2 hits;
// data loads are ~900 cyc HBM (L3 swept by the fill); unroll-2 gave ~1 iter
// of lookahead. Fix (single variable, prep unchanged): explicit pipeline —
// double-buffered Wt chunk prefetch (it+1 loads issued before it's FMAs) +
// depth-4 rolling data prefetch. All statically indexed under full unroll.
// VGPR ~150 fits (256,2); occupancy unchanged 8 waves/CU.
// ---------------------------------------------------------------------------

__global__ __launch_bounds__(256) void prep_kernel(
        const float* __restrict__ W, float* __restrict__ Wt,
        float* __restrict__ G, float* __restrict__ out) {
    if (blockIdx.x < 30) {
        // ---- transpose: output float4 id c covers rows d=4m..4m+3, class k.
        if (blockIdx.x == 0 && threadIdx.x == 0) out[0] = 0.0f;
        const int c = blockIdx.x * 256 + threadIdx.x;   // 7680 = 30*256 exactly
        const int k = c / NF;
        const int m = c - k * NF;
        float4 v;
        v.x = W[(4 * m + 0) * NC + k];
        v.y = W[(4 * m + 1) * NC + k];
        v.z = W[(4 * m + 2) * NC + k];
        v.w = W[(4 * m + 3) * NC + k];
        reinterpret_cast<float4*>(Wt)[c] = v;
    } else {
        // ---- Gram upper-triangle entry (j,k) straight from W (L2-hot).
        int e = blockIdx.x - 30, j = 0;
        while (e >= NC - j) { e -= NC - j; ++j; }
        const int k = j + e;
        float acc = 0.0f;
        for (int d = threadIdx.x; d < ND; d += 256)
            acc = fmaf(W[d * NC + j], W[d * NC + k], acc);
        #pragma unroll
        for (int off = 32; off > 0; off >>= 1) acc += __shfl_xor(acc, off, 64);
        __shared__ float part[4];
        if ((threadIdx.x & 63) == 0) part[threadIdx.x >> 6] = acc;
        __syncthreads();
        if (threadIdx.x == 0) {
            const float g = part[0] + part[1] + part[2] + part[3];
            G[j * NC + k] = g;
            G[k * NC + j] = g;
        }
    }
}

// Main: 512 blocks x 256 threads; wave owns 2 samples. Explicitly software-
// pipelined: Wt chunk double-buffer + depth-4 data prefetch.
__global__ __launch_bounds__(256, 2) void main_kernel(
        const float* __restrict__ data, const float* __restrict__ Wt,
        const float* __restrict__ G, float* __restrict__ out) {
    __shared__ float Gs[100];
    __shared__ float regs[8];

    const int tid  = threadIdx.x;
    const int lane = tid & 63;
    const int wv   = tid >> 6;

    if (tid < 100) Gs[tid] = G[tid];
    __syncthreads();

    const int s0 = blockIdx.x * 8 + wv * 2;          // this wave's 2 samples
    const float4* d0 = reinterpret_cast<const float4*>(data) + (size_t)s0 * NF;
    const float4* d1 = d0 + NF;
    const float4* Wt4 = reinterpret_cast<const float4*>(Wt);

    float acc[2][NC];
    #pragma unroll
    for (int s = 0; s < 2; ++s)
        #pragma unroll
        for (int k = 0; k < NC; ++k) acc[s][k] = 0.0f;

    // Prologue: 4 iterations of data in flight + Wt chunk 0.
    float4 xb0[4], xb1[4];
    #pragma unroll
    for (int p = 0; p < 4; ++p) {
        xb0[p] = d0[p * 64 + lane];
        xb1[p] = d1[p * 64 + lane];
    }
    float4 wq[2][NC];
    #pragma unroll
    for (int k = 0; k < NC; ++k) wq[0][k] = Wt4[k * NF + lane];

    #pragma unroll
    for (int it = 0; it < 12; ++it) {
        const int cur = it & 1, nxt = cur ^ 1;     // static after unroll
        // Prefetch next Wt chunk (L2 latency hides under this iter's FMAs).
        if (it < 11) {
            const int fn = (it + 1) * 64 + lane;
            #pragma unroll
            for (int k = 0; k < NC; ++k) wq[nxt][k] = Wt4[k * NF + fn];
        }
        const int slot = it & 3;                   // static after unroll
        const float4 x0 = xb0[slot], x1 = xb1[slot];
        // Refill the data slot 4 iterations ahead (HBM latency hidden).
        if (it < 8) {
            xb0[slot] = d0[(it + 4) * 64 + lane];
            xb1[slot] = d1[(it + 4) * 64 + lane];
        }
        #pragma unroll
        for (int k = 0; k < NC; ++k) {
            const float4 wt = wq[cur][k];
            acc[0][k] = fmaf(x0.x, wt.x, acc[0][k]);
            acc[0][k] = fmaf(x0.y, wt.y, acc[0][k]);
            acc[0][k] = fmaf(x0.z, wt.z, acc[0][k]);
            acc[0][k] = fmaf(x0.w, wt.w, acc[0][k]);
            acc[1][k] = fmaf(x1.x, wt.x, acc[1][k]);
            acc[1][k] = fmaf(x1.y, wt.y, acc[1][k]);
            acc[1][k] = fmaf(x1.z, wt.z, acc[1][k]);
            acc[1][k] = fmaf(x1.w, wt.w, acc[1][k]);
        }
    }

    // In-wave butterfly: every lane ends with full z[10] for both samples.
    #pragma unroll
    for (int s = 0; s < 2; ++s)
        #pragma unroll
        for (int k = 0; k < NC; ++k) {
            float v = acc[s][k];
            #pragma unroll
            for (int off = 32; off > 0; off >>= 1) v += __shfl_xor(v, off, 64);
            acc[s][k] = v;
        }

    // Analytic epilogue: lane 0 -> sample s0, lane 1 -> sample s0+1.
    if (lane < 2) {
        float z[NC];
        #pragma unroll
        for (int k = 0; k < NC; ++k) z[k] = (lane == 0) ? acc[0][k] : acc[1][k];

        float zm = z[0];
        #pragma unroll
        for (int k = 1; k < NC; ++k) zm = fmaxf(zm, z[k]);
        float e[NC], Zs = 0.0f;
        #pragma unroll
        for (int k = 0; k < NC; ++k) { e[k] = expf(z[k] - zm); Zs += e[k]; }
        const float inv = 1.0f / Zs;

        float sg[NC], p[NC], sq[NC], u[NC];
        #pragma unroll
        for (int k = 0; k < NC; ++k) {
            sg[k] = e[k] * inv;                 // softmax probs (sigma)
            p[k]  = kAlpha * sg[k] + kNumStab;  // stabilized probs
            sq[k] = sqrtf(p[k]);                // s
            u[k]  = sg[k] / sq[k];              // sigma / s
        }
        const float qd = 1.0f - sq[NM];

        // v = G*sigma, t = sigma^T G sigma
        float v[NC], t = 0.0f;
        #pragma unroll
        for (int k = 0; k < NC; ++k) {
            float a = 0.0f;
            #pragma unroll
            for (int j = 0; j < NC; ++j) a = fmaf(Gs[k * NC + j], sg[j], a);
            v[k] = a;
            t = fmaf(sg[k], a, t);
        }
        const float vM = v[NM], uM = u[NM];
        const float QMM = Gs[NC * NC - 1] - 2.0f * vM + t;

        float sumJ = 0.0f;
        #pragma unroll
        for (int i = 0; i < NM; ++i) {
            const float Qii = Gs[i * NC + i] - 2.0f * v[i] + t;
            const float QiM = Gs[i * NC + NM] - v[i] - vM + t;
            const float r = sq[i] / qd;
            sumJ += u[i] * u[i] * Qii
                  + 2.0f * u[i] * uM * r * QiM
                  + uM * uM * r * r * QMM;
        }
        const float jn = (kAlpha / qd) * sqrtf(fmaxf(sumJ, 0.0f));

        float ssum = 0.0f;
        #pragma unroll
        for (int k = 0; k < NC; ++k) ssum += sq[k];
        const float ac = fminf(1.0f, fmaxf(-1.0f, ssum * kInvSqrtC));
        const float delta = 2.0f * acosf(ac);

        float psum = 0.0f;
        #pragma unroll
        for (int k = 0; k < NM; ++k) psum += p[k];
        const float rho = (2.0f * qd - psum) / qd;

        const float a = jn - delta / (rho * kEps);
        regs[wv * 2 + lane] = (a > 0.0f) ? a : expm1f(a);
    }
    __syncthreads();
    if (tid == 0) {
        float bs = 0.0f;
        #pragma unroll
        for (int i = 0; i < 8; ++i) bs += regs[i];
        atomicAdd(out, bs * (1.0f / (float)NB));
    }
}

extern "C" void kernel_launch(void* const* d_in, const int* in_sizes, int n_in,
                              void* d_out, int out_size, void* d_ws, size_t ws_size,
                              hipStream_t stream) {
    const float* data = (const float*)d_in[0];
    const float* W    = (const float*)d_in[1];
    float* out = (float*)d_out;
    float* Wt  = (float*)d_ws;            // NC*ND floats (120 KB)
    float* G   = Wt + NC * ND;            // 100 floats

    // prep zeroes out (replaces hipMemsetAsync), transposes W, computes Gram.
    prep_kernel<<<30 + (NC * (NC + 1)) / 2, 256, 0, stream>>>(W, Wt, G, out);
    main_kernel<<<NB / 8, 256, 0, stream>>>(data, Wt, G, out);
}